// Round 1
// baseline (137.880 us; speedup 1.0000x reference)
//
#include <hip/hip_runtime.h>
#include <hip/hip_bf16.h>

#define N_NODES 50000
#define N_EDGES 1200000
#define N_TILES (N_NODES / 16)   // 3125, exact
#define W1T_STRIDE 72            // bf16 elems per j-row in LDS (16B aligned)
#define K1_BLOCKS 782            // 3128 waves >= 3125 tiles, one-shot

#define N_BUCKETS 196            // ceil(50000/256) row buckets of 256 nodes
#define BUCKET_CAP 7168          // mean 6122, sigma ~78 -> 13 sigma headroom
#define EDGES_PER_BLOCK 9600     // R10: 5x bigger bins -> 5x fewer cursor atomics
#define KA_BLOCKS 125            // 1.2M / 9600 exact
#define D1_BLOCKS (K1_BLOCKS + KA_BLOCKS)   // 907: precompute + bin fused
#define KB_SPLIT 4               // segments per bucket in the MLP kernel

typedef __attribute__((ext_vector_type(8))) short short8;   // 8 bf16
typedef __attribute__((ext_vector_type(4))) float floatx4;  // MFMA acc

__device__ __forceinline__ unsigned short f32_to_bf16(float f) {
    unsigned int v = __float_as_uint(f);
    unsigned int r = v + 0x7FFFu + ((v >> 16) & 1u);
    return (unsigned short)(r >> 16);
}
__device__ __forceinline__ unsigned int pack_bf16x2(float lo, float hi) {
    return (unsigned int)f32_to_bf16(lo) | ((unsigned int)f32_to_bf16(hi) << 16);
}

// ---------------------------------------------------------------------------
// Dispatch 1 (fused): blocks [0, K1_BLOCKS) do layer-1 precompute (MFMA GEMM,
// R4-proven) + zero `out`; blocks [K1_BLOCKS, D1_BLOCKS) bin edge IDs by row
// bucket. R10: EDGES_PER_BLOCK 1920->9600 (125 binning blocks): cursor-
// reservation atomics drop 122.5K->24.5K (they all land in 13 cache lines ->
// cross-CU serialization), and per-bucket write runs grow ~10->~49 u32.
// LDS union grows to 20.8 KB -> still 7 blocks/CU.
// ---------------------------------------------------------------------------
__global__ __launch_bounds__(256) void fused_pre_bin(
    const float* __restrict__ x, const float* __restrict__ W1,
    const float* __restrict__ b1,
    const int* __restrict__ row, const int* __restrict__ col,
    unsigned short* __restrict__ P1, unsigned short* __restrict__ P2,
    unsigned int* __restrict__ buf, int* __restrict__ cursor,
    float* __restrict__ out)
{
    __shared__ union {
        unsigned short W1t[64 * W1T_STRIDE];                // 9216 B
        struct {
            unsigned short rankv[EDGES_PER_BLOCK];          // 19200 B
            int hist[N_BUCKETS];                            //   784 B
            int base[N_BUCKETS];                            //   784 B
        } bin;
    } sh;

    const int tid = threadIdx.x;
    const int bid = blockIdx.x;

    if (bid < K1_BLOCKS) {
        // ================= precompute path =================
        const int gtid = bid * 256 + tid;
        for (int i = gtid; i < N_NODES; i += K1_BLOCKS * 256)
            out[i] = 0.0f;   // KB atomically accumulates into out

        for (int e = tid; e < 128 * 32; e += 256) {
            const int kp = e >> 5, jp = e & 31;
            sh.W1t[((kp < 64) ? jp : jp + 32) * W1T_STRIDE + (kp & 63)] =
                f32_to_bf16(W1[e]);
        }
        __syncthreads();

        const int lane = tid & 63;
        const int n = lane & 15;
        const int q = lane >> 4;

        const int tile = bid * 4 + (tid >> 6);
        if (tile >= N_TILES) return;

        short8 bw[4][2];
        #pragma unroll
        for (int G = 0; G < 4; ++G)
            #pragma unroll
            for (int h = 0; h < 2; ++h)
                bw[G][h] = *(const short8*)
                    &sh.W1t[(n + 16 * G) * W1T_STRIDE + h * 32 + q * 8];
        const float bias0 = b1[n], bias1 = b1[n + 16];

        const int node = tile * 16 + n;
        const float4* xp  = (const float4*)(x + (size_t)node * 64 + q * 8);
        const float4 xa = xp[0], xb = xp[1];
        const float4* xp2 = (const float4*)(x + (size_t)node * 64 + 32 + q * 8);
        const float4 xc = xp2[0], xd = xp2[1];

        short8 a0, a1;
        a0[0] = (short)f32_to_bf16(xa.x); a0[1] = (short)f32_to_bf16(xa.y);
        a0[2] = (short)f32_to_bf16(xa.z); a0[3] = (short)f32_to_bf16(xa.w);
        a0[4] = (short)f32_to_bf16(xb.x); a0[5] = (short)f32_to_bf16(xb.y);
        a0[6] = (short)f32_to_bf16(xb.z); a0[7] = (short)f32_to_bf16(xb.w);
        a1[0] = (short)f32_to_bf16(xc.x); a1[1] = (short)f32_to_bf16(xc.y);
        a1[2] = (short)f32_to_bf16(xc.z); a1[3] = (short)f32_to_bf16(xc.w);
        a1[4] = (short)f32_to_bf16(xd.x); a1[5] = (short)f32_to_bf16(xd.y);
        a1[6] = (short)f32_to_bf16(xd.z); a1[7] = (short)f32_to_bf16(xd.w);

        floatx4 acc[4];
        #pragma unroll
        for (int G = 0; G < 4; ++G) {
            const float bi = (G == 0) ? bias0 : (G == 1) ? bias1 : 0.0f;
            acc[G] = (floatx4){bi, bi, bi, bi};
            acc[G] = __builtin_amdgcn_mfma_f32_16x16x32_bf16(a0, bw[G][0], acc[G], 0, 0, 0);
            acc[G] = __builtin_amdgcn_mfma_f32_16x16x32_bf16(a1, bw[G][1], acc[G], 0, 0, 0);
        }
        unsigned int* P1d = (unsigned int*)P1;
        unsigned int* P2d = (unsigned int*)P2;
        #pragma unroll
        for (int r = 0; r < 4; ++r) {
            const int nr = tile * 16 + q * 4 + r;
            P1d[(size_t)nr * 16 + n] = pack_bf16x2(acc[0][r], acc[1][r]);
            P2d[(size_t)nr * 16 + n] = pack_bf16x2(acc[2][r], acc[3][r]);
        }
    } else {
        // ================= binning path =================
        for (int b = tid; b < N_BUCKETS; b += 256) sh.bin.hist[b] = 0;
        __syncthreads();

        const int blockStart = (bid - K1_BLOCKS) * EDGES_PER_BLOCK;

        for (int i = tid; i < EDGES_PER_BLOCK; i += 256) {
            const int r = row[blockStart + i];
            sh.bin.rankv[i] = (unsigned short)atomicAdd(&sh.bin.hist[r >> 8], 1);
        }
        __syncthreads();

        for (int b = tid; b < N_BUCKETS; b += 256)
            sh.bin.base[b] = atomicAdd(&cursor[b], sh.bin.hist[b]);
        __syncthreads();

        for (int i = tid; i < EDGES_PER_BLOCK; i += 256) {
            const int r = row[blockStart + i];
            const int c = col[blockStart + i];
            const int bin = r >> 8;
            buf[(size_t)bin * BUCKET_CAP + sh.bin.base[bin] + (int)sh.bin.rankv[i]] =
                ((unsigned int)(r & 255) << 24) | (unsigned int)c;
        }
    }
}

// ---------------------------------------------------------------------------
// Dispatch 2 (KB): per-bucket MLP (layers 2+3, MFMA) + LDS fp32 row reduce.
// R10: the chunk loop is now a 3-deep software pipeline. buf/P2 were written
// by other XCDs (per-XCD L2 not shared), so first-touch loads are L3/HBM
// latency (~500-900 cy); previously the buf->index->gather chain was fully
// exposed every iteration. Now: issue entries(ch+64) and gathers(ch+32)
// BEFORE computing ch, so both load levels hide under compute.
// Repack also moved to pairwise math + v_cvt_pk_bf16_f32 (same RTNE bits),
// ~128 -> ~56 VALU ops per chunk.
// ---------------------------------------------------------------------------
struct EntS {                 // stage A: raw bucket entries for one chunk
    unsigned int g0, g1;      // gather-lane entries (tail-clamped)
    unsigned int o;           // owner-lane entry (n<8 only)
    int ov;                   // owner valid
};
struct GatS {                 // stage B: gathered operands for one chunk
    short8 v1a, v2a, v1b, v2b;
    float u2;
    int r2;
};

__global__ __launch_bounds__(512) void bucket_mlp(
    const float* __restrict__ u,
    const float* __restrict__ W2, const float* __restrict__ b2,
    const float* __restrict__ W3, const float* __restrict__ b3,
    const unsigned short* __restrict__ P1, const unsigned short* __restrict__ P2,
    const unsigned int* __restrict__ buf, const int* __restrict__ cursor,
    float* __restrict__ out)
{
    __shared__ float accs[256];
    const int tid = threadIdx.x;
    if (tid < 256) accs[tid] = 0.0f;

    const int b = blockIdx.x >> 2;              // bucket
    const int s = blockIdx.x & (KB_SPLIT - 1);  // segment

    const int lane = tid & 63;
    const int n = lane & 15;
    const int q = lane >> 4;
    const int wave = tid >> 6;                  // 0..7

    // W2/W3 fragments with the P permutation F(q,i)
    short8 bf0, bf1;
    #pragma unroll
    for (int i = 0; i < 8; ++i) {
        const int F = q * 4 + (i >> 1) + 16 * (i & 1);
        bf0[i] = (short)f32_to_bf16(W2[F * 32 + n]);
        bf1[i] = (short)f32_to_bf16(W2[F * 32 + n + 16]);
    }
    const float w3n0 = W3[n], w3n1 = W3[n + 16];
    const float b2n0 = b2[n], b2n1 = b2[n + 16];
    const float bias3 = b3[0];

    __syncthreads();

    const int cnt = cursor[b];
    const unsigned int* bb = buf + (size_t)b * BUCKET_CAP;
    const unsigned short* P1b = P1 + (size_t)b * 256 * 32;  // bucket row window
    const int nch = (cnt + 31) >> 5;

    // ---- pipeline stage helpers ----
    auto load_ent = [&](int ch) -> EntS {
        EntS E;
        const int base0 = ch * 32;
        int e0 = base0 + n;        if (e0 >= cnt) e0 = cnt - 1;
        int e1 = base0 + 16 + n;   if (e1 >= cnt) e1 = cnt - 1;
        E.g0 = bb[e0];
        E.g1 = bb[e1];
        E.o = 0u; E.ov = 0;
        if (n < 8) {
            const int eloc = base0 + 16 * (n >> 2) + 4 * q + (n & 3);
            E.ov = (eloc < cnt);
            E.o = bb[E.ov ? eloc : 0];
        }
        return E;
    };
    auto load_gat = [&](const EntS& E) -> GatS {
        GatS G;
        G.v1a = *(const short8*)(P1b + (size_t)(E.g0 >> 24) * 32 + q * 8);
        G.v2a = *(const short8*)(P2  + (size_t)(E.g0 & 0x1FFFFu) * 32 + q * 8);
        G.v1b = *(const short8*)(P1b + (size_t)(E.g1 >> 24) * 32 + q * 8);
        G.v2b = *(const short8*)(P2  + (size_t)(E.g1 & 0x1FFFFu) * 32 + q * 8);
        G.r2 = (int)(E.o >> 24);
        G.u2 = E.ov ? u[E.o & 0x1FFFFu] : 0.0f;
        return G;
    };
    auto compute = [&](const GatS& G) {
        float tr[2][4];
        #pragma unroll
        for (int t = 0; t < 2; ++t) {
            const short8 v1 = t ? G.v1b : G.v1a;
            const short8 v2 = t ? G.v2b : G.v2a;
            union VU { short8 s; unsigned int w[4]; };
            VU x1, x2, ar;
            x1.s = v1; x2.s = v2;
            #pragma unroll
            for (int i = 0; i < 4; ++i) {
                const unsigned int w1 = x1.w[i], w2 = x2.w[i];
                float lo = __uint_as_float(w1 << 16) + __uint_as_float(w2 << 16);
                float hi = __uint_as_float(w1 & 0xFFFF0000u) + __uint_as_float(w2 & 0xFFFF0000u);
                lo = fmaxf(lo, 0.0f);
                hi = fmaxf(hi, 0.0f);
                union { __hip_bfloat162 h; unsigned int u32; } cv;
                cv.h = __float22bfloat162_rn(make_float2(lo, hi));
                ar.w[i] = cv.u32;
            }
            const short8 a = ar.s;
            floatx4 d0 = {b2n0, b2n0, b2n0, b2n0};
            floatx4 d1 = {b2n1, b2n1, b2n1, b2n1};
            d0 = __builtin_amdgcn_mfma_f32_16x16x32_bf16(a, bf0, d0, 0, 0, 0);
            d1 = __builtin_amdgcn_mfma_f32_16x16x32_bf16(a, bf1, d1, 0, 0, 0);
            #pragma unroll
            for (int r = 0; r < 4; ++r)
                tr[t][r] = fmaxf(d0[r], 0.0f) * w3n0 + fmaxf(d1[r], 0.0f) * w3n1;
        }

        #pragma unroll
        for (int mask = 1; mask < 16; mask <<= 1) {
            #pragma unroll
            for (int t = 0; t < 2; ++t)
                #pragma unroll
                for (int r = 0; r < 4; ++r)
                    tr[t][r] += __shfl_xor(tr[t][r], mask, 64);
        }

        if (n < 8) {
            const float va0 = (n & 4) ? tr[1][0] : tr[0][0];
            const float va1 = (n & 4) ? tr[1][1] : tr[0][1];
            const float va2 = (n & 4) ? tr[1][2] : tr[0][2];
            const float va3 = (n & 4) ? tr[1][3] : tr[0][3];
            const float vb0 = (n & 2) ? va2 : va0;
            const float vb1 = (n & 2) ? va3 : va1;
            const float v   = (n & 1) ? vb1 : vb0;
            atomicAdd(&accs[G.r2], (v + bias3) * G.u2);
        }
    };

    // ---- 3-deep pipelined chunk loop ----
    int c0 = s * 8 + wave;         // current chunk
    if (c0 < nch) {
        int c1 = c0 + 32;          // next chunk
        EntS eCur = load_ent(c0);
        EntS eNxt = (c1 < nch) ? load_ent(c1) : eCur;
        GatS gCur = load_gat(eCur);
        for (;;) {
            const int c2 = c1 + 32;
            EntS eN2  = (c2 < nch) ? load_ent(c2) : eNxt;   // entries 2 ahead
            GatS gNxt = (c1 < nch) ? load_gat(eNxt) : gCur; // gathers 1 ahead
            compute(gCur);                                  // hides both
            if (c1 >= nch) break;
            c1 = c2;
            eNxt = eN2;
            gCur = gNxt;
        }
    }

    __syncthreads();

    if (tid < 256) {
        const int node = b * 256 + tid;
        if (node < N_NODES) atomicAdd(out + node, accs[tid]);
    }
}

extern "C" void kernel_launch(void* const* d_in, const int* in_sizes, int n_in,
                              void* d_out, int out_size, void* d_ws, size_t ws_size,
                              hipStream_t stream)
{
    const float* x    = (const float*)d_in[0];
    const int*   eidx = (const int*)  d_in[1];   // [2, E] int32
    const float* u    = (const float*)d_in[2];
    const float* W1   = (const float*)d_in[3];
    const float* b1   = (const float*)d_in[4];
    const float* W2   = (const float*)d_in[5];
    const float* b2   = (const float*)d_in[6];
    const float* W3   = (const float*)d_in[7];
    const float* b3   = (const float*)d_in[8];

    const int* row = eidx;
    const int* col = eidx + N_EDGES;

    // ws layout: P1 3.2MB | P2 3.2MB | buf 5.62MB | cursor 784B
    unsigned short* P1 = (unsigned short*)d_ws;
    unsigned short* P2 = (unsigned short*)((char*)d_ws + (size_t)N_NODES * 64);
    unsigned int*  buf = (unsigned int*)((char*)d_ws + (size_t)N_NODES * 128);
    int* cursor = (int*)((char*)d_ws + (size_t)N_NODES * 128
                         + (size_t)N_BUCKETS * BUCKET_CAP * 4);
    float* out = (float*)d_out;

    // zero bucket cursors (784 B, must precede the binning blocks of D1)
    hipMemsetAsync(cursor, 0, N_BUCKETS * sizeof(int), stream);

    // D1: precompute P1/P2 + zero out  ||  bin edge IDs (concurrent halves)
    fused_pre_bin<<<D1_BLOCKS, 256, 0, stream>>>(
        x, W1, b1, row, col, P1, P2, buf, cursor, out);

    // D2: per-bucket MLP + LDS reduce -> out (512-thread blocks)
    bucket_mlp<<<N_BUCKETS * KB_SPLIT, 512, 0, stream>>>(
        u, W2, b2, W3, b3, P1, P2, buf, cursor, out);
}